// Round 7
// baseline (136.993 us; speedup 1.0000x reference)
//
#include <hip/hip_runtime.h>
#include <hip/hip_fp16.h>

// Soft Voronoi rasterizer: out[y][x][c] = w*s0.rgb + (1-w)*s1.rgb,
// w = sigmoid((d1-d0)*0.25), d_i = |pixel_center - site_i.xy|^2.
// Constants fixed by setup_inputs(): H=W=2048, N_SITES=65536.
//
// Ladder: R1 naive-ish 86us -> R3 packed 16B records (1 dwordx4/gather) 56us
// -> R4 cached stores (write 78->49MB, dur flat: not write-bound) -> R6 sc0
// L1-bypass gathers 49.5us (-9%: L1 occupancy minor). R7 theory: residual is
// gather LATENCY under low MLP (8 in-flight/wave, one vmcnt(0) drain, ~18
// waves/CU). This round: 8 px/thread = 16 gathers in flight, split
// vmcnt(8)/vmcnt(0) waits so px0-3 compute overlaps the second load group.

#define IMG_W 2048
#define IMG_H 2048
#define N_PIX (IMG_W * IMG_H)
#define N_SITES 65536
#define INV_SCALE_SQ 0.25f

typedef int   vint4   __attribute__((ext_vector_type(4)));
typedef float vfloat4 __attribute__((ext_vector_type(4)));

// ---- pre-pass: [N,5] f32 -> [N] {x f32, y f32, (r,g) half2, (b,0) half2} ----
__global__ __launch_bounds__(256) void repack_sites(
    const float* __restrict__ sites, vfloat4* __restrict__ packed)
{
    const int i = blockIdx.x * blockDim.x + threadIdx.x;  // < N_SITES
    const float* s = sites + (size_t)i * 5;
    const __half2 rg = __floats2half2_rn(s[2], s[3]);
    const __half2 b0 = __floats2half2_rn(s[4], 0.0f);
    vfloat4 v;
    v.x = s[0];
    v.y = s[1];
    v.z = __uint_as_float(*reinterpret_cast<const unsigned int*>(&rg));
    v.w = __uint_as_float(*reinterpret_cast<const unsigned int*>(&b0));
    packed[i] = v;
}

__device__ __forceinline__ float3 unpack_rgb(const vfloat4& rec) {
    const unsigned int zu = __float_as_uint(rec.z);
    const unsigned int wu = __float_as_uint(rec.w);
    const __half2 rg = *reinterpret_cast<const __half2*>(&zu);
    const __half2 b0 = *reinterpret_cast<const __half2*>(&wu);
    const float2 rgf = __half22float2(rg);
    return make_float3(rgf.x, rgf.y, __half2float(b0.x));
}

__device__ __forceinline__ void shade4(
    const vfloat4* r0, const vfloat4* r1,
    float px_base, float py, float* res /*12 floats*/)
{
#pragma unroll
    for (int i = 0; i < 4; ++i) {
        const float px = px_base + (float)i;
        const float dx0 = px - r0[i].x, dy0 = py - r0[i].y;
        const float dx1 = px - r1[i].x, dy1 = py - r1[i].y;
        const float d0 = dx0 * dx0 + dy0 * dy0;
        const float d1 = dx1 * dx1 + dy1 * dy1;
        const float t = (d1 - d0) * INV_SCALE_SQ;
        // stable at both tails: expf(+huge)=inf -> w=0; expf(-huge)=0 -> w=1
        const float w = 1.0f / (1.0f + __expf(-t));
        const float wc = 1.0f - w;
        const float3 cA = unpack_rgb(r0[i]);
        const float3 cB = unpack_rgb(r1[i]);
        res[i * 3 + 0] = w * cA.x + wc * cB.x;
        res[i * 3 + 1] = w * cA.y + wc * cB.y;
        res[i * 3 + 2] = w * cA.z + wc * cB.z;
    }
}

// ---- main: 8 pixels/thread; 16 sc0 gathers in flight, split-wait pipeline ----
__global__ __launch_bounds__(256) void voronoi_soft_kernel(
    const vfloat4* __restrict__ packed, // [N_SITES] repacked records
    const int*     __restrict__ cand0,  // [H, W]
    const int*     __restrict__ cand1,  // [H, W]
    float*         __restrict__ out)    // [H, W, 3]
{
    const int tid = blockIdx.x * blockDim.x + threadIdx.x;
    const int pix = tid * 8;

    // streamed once: nontemporal so they don't evict the site table from L2
    const vint4* c0p = reinterpret_cast<const vint4*>(cand0 + pix);
    const vint4* c1p = reinterpret_cast<const vint4*>(cand1 + pix);
    const vint4 c0lo = __builtin_nontemporal_load(c0p);
    const vint4 c0hi = __builtin_nontemporal_load(c0p + 1);
    const vint4 c1lo = __builtin_nontemporal_load(c1p);
    const vint4 c1hi = __builtin_nontemporal_load(c1p + 1);

    // byte offsets into the 16B-record table (idx<<4), saddr-form loads keep
    // address cost to 1 VGPR per gather instead of a 64-bit pair.
    const int oa0[4] = {c0lo.x << 4, c0lo.y << 4, c0lo.z << 4, c0lo.w << 4};
    const int oa1[4] = {c1lo.x << 4, c1lo.y << 4, c1lo.z << 4, c1lo.w << 4};
    const int ob0[4] = {c0hi.x << 4, c0hi.y << 4, c0hi.z << 4, c0hi.w << 4};
    const int ob1[4] = {c1hi.x << 4, c1hi.y << 4, c1hi.z << 4, c1hi.w << 4};

    vfloat4 a0[4], a1[4];  // px 0-3: cand0 / cand1 records
    vfloat4 b0[4], b1[4];  // px 4-7

    // Block A: issue 8 sc0 gathers for px0-3 (no wait). "=&v" early-clobber:
    // outputs must not alias later loads' offset regs (R5 fault lesson).
    asm volatile(
        "global_load_dwordx4 %0, %8, %16 sc0\n\t"
        "global_load_dwordx4 %1, %9, %16 sc0\n\t"
        "global_load_dwordx4 %2, %10, %16 sc0\n\t"
        "global_load_dwordx4 %3, %11, %16 sc0\n\t"
        "global_load_dwordx4 %4, %12, %16 sc0\n\t"
        "global_load_dwordx4 %5, %13, %16 sc0\n\t"
        "global_load_dwordx4 %6, %14, %16 sc0\n\t"
        "global_load_dwordx4 %7, %15, %16 sc0"
        : "=&v"(a0[0]), "=&v"(a0[1]), "=&v"(a0[2]), "=&v"(a0[3]),
          "=&v"(a1[0]), "=&v"(a1[1]), "=&v"(a1[2]), "=&v"(a1[3])
        : "v"(oa0[0]), "v"(oa0[1]), "v"(oa0[2]), "v"(oa0[3]),
          "v"(oa1[0]), "v"(oa1[1]), "v"(oa1[2]), "v"(oa1[3]),
          "s"(packed)
        : "memory");

    // Block B: issue 8 more gathers for px4-7, then wait only until the
    // first 8 have landed (vmcnt(8)). a* passed "+v" so their consumers are
    // ordered after this block.
    asm volatile(
        "global_load_dwordx4 %0, %16, %24 sc0\n\t"
        "global_load_dwordx4 %1, %17, %24 sc0\n\t"
        "global_load_dwordx4 %2, %18, %24 sc0\n\t"
        "global_load_dwordx4 %3, %19, %24 sc0\n\t"
        "global_load_dwordx4 %4, %20, %24 sc0\n\t"
        "global_load_dwordx4 %5, %21, %24 sc0\n\t"
        "global_load_dwordx4 %6, %22, %24 sc0\n\t"
        "global_load_dwordx4 %7, %23, %24 sc0\n\t"
        "s_waitcnt vmcnt(8)"
        : "=&v"(b0[0]), "=&v"(b0[1]), "=&v"(b0[2]), "=&v"(b0[3]),
          "=&v"(b1[0]), "=&v"(b1[1]), "=&v"(b1[2]), "=&v"(b1[3]),
          "+v"(a0[0]), "+v"(a0[1]), "+v"(a0[2]), "+v"(a0[3]),
          "+v"(a1[0]), "+v"(a1[1]), "+v"(a1[2]), "+v"(a1[3])
        : "v"(ob0[0]), "v"(ob0[1]), "v"(ob0[2]), "v"(ob0[3]),
          "v"(ob1[0]), "v"(ob1[1]), "v"(ob1[2]), "v"(ob1[3]),
          "s"(packed)
        : "memory");

    // all 8 pixels share a row (W divisible by 8)
    const float py = (float)(pix >> 11) + 0.5f;
    const float px_base = (float)(pix & (IMG_W - 1)) + 0.5f;

    float res[24];
    shade4(a0, a1, px_base, py, res);          // overlaps second load group

    // Block C: drain the remaining 8 loads; b* consumers ordered after.
    asm volatile(
        "s_waitcnt vmcnt(0)"
        : "+v"(b0[0]), "+v"(b0[1]), "+v"(b0[2]), "+v"(b0[3]),
          "+v"(b1[0]), "+v"(b1[1]), "+v"(b1[2]), "+v"(b1[3]));

    shade4(b0, b1, px_base + 4.0f, py, res + 12);

    // normal cached stores: L2 write-back merges the partial-line pattern
    vfloat4* o = reinterpret_cast<vfloat4*>(out + (size_t)pix * 3);
#pragma unroll
    for (int k = 0; k < 6; ++k) {
        vfloat4 v = {res[k * 4 + 0], res[k * 4 + 1], res[k * 4 + 2], res[k * 4 + 3]};
        o[k] = v;
    }
}

// ---- fallback (ws too small): round-1 style direct gather, known-correct ----
__global__ __launch_bounds__(256) void voronoi_soft_fallback(
    const float* __restrict__ sites,
    const int*   __restrict__ cand0,
    const int*   __restrict__ cand1,
    float*       __restrict__ out)
{
    const int tid = blockIdx.x * blockDim.x + threadIdx.x;
    const int pix = tid * 4;
    const int4 c0 = *reinterpret_cast<const int4*>(cand0 + pix);
    const int4 c1 = *reinterpret_cast<const int4*>(cand1 + pix);
    const int idx0[4] = {c0.x, c0.y, c0.z, c0.w};
    const int idx1[4] = {c1.x, c1.y, c1.z, c1.w};
    const float py = (float)(pix >> 11) + 0.5f;
    const float px_base = (float)(pix & (IMG_W - 1)) + 0.5f;
    float res[12];
#pragma unroll
    for (int i = 0; i < 4; ++i) {
        const float px = px_base + (float)i;
        const float* s0 = sites + (size_t)idx0[i] * 5;
        const float* s1 = sites + (size_t)idx1[i] * 5;
        const float dx0 = px - s0[0], dy0 = py - s0[1];
        const float dx1 = px - s1[0], dy1 = py - s1[1];
        const float d0 = dx0 * dx0 + dy0 * dy0;
        const float d1 = dx1 * dx1 + dy1 * dy1;
        const float w = 1.0f / (1.0f + __expf(-(d1 - d0) * INV_SCALE_SQ));
        const float wc = 1.0f - w;
        res[i * 3 + 0] = w * s0[2] + wc * s1[2];
        res[i * 3 + 1] = w * s0[3] + wc * s1[3];
        res[i * 3 + 2] = w * s0[4] + wc * s1[4];
    }
    float4* o = reinterpret_cast<float4*>(out + (size_t)pix * 3);
    o[0] = make_float4(res[0], res[1], res[2], res[3]);
    o[1] = make_float4(res[4], res[5], res[6], res[7]);
    o[2] = make_float4(res[8], res[9], res[10], res[11]);
}

extern "C" void kernel_launch(void* const* d_in, const int* in_sizes, int n_in,
                              void* d_out, int out_size, void* d_ws, size_t ws_size,
                              hipStream_t stream) {
    const float* sites = (const float*)d_in[0];   // [65536, 5]
    const int*   cand0 = (const int*)d_in[1];     // [2048, 2048]
    const int*   cand1 = (const int*)d_in[2];     // [2048, 2048]
    float* out = (float*)d_out;                   // [2048, 2048, 3]

    const size_t packed_bytes = (size_t)N_SITES * sizeof(vfloat4);  // 1 MB
    if (ws_size >= packed_bytes) {
        vfloat4* packed = (vfloat4*)d_ws;
        repack_sites<<<N_SITES / 256, 256, 0, stream>>>(sites, packed);
        const int blocks = N_PIX / (8 * 256);     // 2048
        voronoi_soft_kernel<<<blocks, 256, 0, stream>>>(packed, cand0, cand1, out);
    } else {
        voronoi_soft_fallback<<<N_PIX / (4 * 256), 256, 0, stream>>>(sites, cand0, cand1, out);
    }
}

// Round 8
// 133.331 us; speedup vs baseline: 1.0275x; 1.0275x over previous
//
#include <hip/hip_runtime.h>
#include <hip/hip_fp16.h>

// Soft Voronoi rasterizer: out[y][x][c] = w*s0.rgb + (1-w)*s1.rgb,
// w = sigmoid((d1-d0)*0.25), d_i = |pixel_center - site_i.xy|^2.
// Constants fixed by setup_inputs(): H=W=2048, N_SITES=65536.
//
// Ladder: R1 86us -> R3 packed 16B records (1 dwordx4/gather) 56us -> R4
// cached stores (not write-bound) -> R6 sc0 L1-bypass 49.5us. R7 (8px/thread)
// REGRESSED 55.7us: device-total outstanding requests unchanged (2x MLP x
// 0.5x waves), occupancy fell. R8: back to R6 base; interleave gathers
// pairwise and STAGE the waits (vmcnt 6/4/2/0) so a wave shades px_i as soon
// as its pair lands -> shorter wave lifetime -> faster wave turnover.

#define IMG_W 2048
#define IMG_H 2048
#define N_PIX (IMG_W * IMG_H)
#define N_SITES 65536
#define INV_SCALE_SQ 0.25f

typedef int   vint4   __attribute__((ext_vector_type(4)));
typedef float vfloat4 __attribute__((ext_vector_type(4)));

// ---- pre-pass: [N,5] f32 -> [N] {x f32, y f32, (r,g) half2, (b,0) half2} ----
__global__ __launch_bounds__(256) void repack_sites(
    const float* __restrict__ sites, vfloat4* __restrict__ packed)
{
    const int i = blockIdx.x * blockDim.x + threadIdx.x;  // < N_SITES
    const float* s = sites + (size_t)i * 5;
    const __half2 rg = __floats2half2_rn(s[2], s[3]);
    const __half2 b0 = __floats2half2_rn(s[4], 0.0f);
    vfloat4 v;
    v.x = s[0];
    v.y = s[1];
    v.z = __uint_as_float(*reinterpret_cast<const unsigned int*>(&rg));
    v.w = __uint_as_float(*reinterpret_cast<const unsigned int*>(&b0));
    packed[i] = v;
}

__device__ __forceinline__ float3 unpack_rgb(const vfloat4& rec) {
    const unsigned int zu = __float_as_uint(rec.z);
    const unsigned int wu = __float_as_uint(rec.w);
    const __half2 rg = *reinterpret_cast<const __half2*>(&zu);
    const __half2 b0 = *reinterpret_cast<const __half2*>(&wu);
    const float2 rgf = __half22float2(rg);
    return make_float3(rgf.x, rgf.y, __half2float(b0.x));
}

__device__ __forceinline__ void shade1(
    const vfloat4& rA, const vfloat4& rB,
    float px, float py, float* res /*3 floats*/)
{
    const float dx0 = px - rA.x, dy0 = py - rA.y;
    const float dx1 = px - rB.x, dy1 = py - rB.y;
    const float d0 = dx0 * dx0 + dy0 * dy0;
    const float d1 = dx1 * dx1 + dy1 * dy1;
    const float t = (d1 - d0) * INV_SCALE_SQ;
    // stable at both tails: expf(+huge)=inf -> w=0; expf(-huge)=0 -> w=1
    const float w = 1.0f / (1.0f + __expf(-t));
    const float wc = 1.0f - w;
    const float3 cA = unpack_rgb(rA);
    const float3 cB = unpack_rgb(rB);
    res[0] = w * cA.x + wc * cB.x;
    res[1] = w * cA.y + wc * cB.y;
    res[2] = w * cA.z + wc * cB.z;
}

// ---- main: 4 pixels/thread; 8 sc0 gathers interleaved pairwise, staged
//      vmcnt(6/4/2/0) waits so shading starts when the first pair lands ----
__global__ __launch_bounds__(256) void voronoi_soft_kernel(
    const vfloat4* __restrict__ packed, // [N_SITES] repacked records
    const int*     __restrict__ cand0,  // [H, W]
    const int*     __restrict__ cand1,  // [H, W]
    float*         __restrict__ out)    // [H, W, 3]
{
    const int tid = blockIdx.x * blockDim.x + threadIdx.x;
    const int pix = tid * 4;

    // streamed once: nontemporal so they don't evict the site table from L2
    const vint4 c0 = __builtin_nontemporal_load(reinterpret_cast<const vint4*>(cand0 + pix));
    const vint4 c1 = __builtin_nontemporal_load(reinterpret_cast<const vint4*>(cand1 + pix));

    // byte offsets into the 16B-record table; saddr-form loads (1 VGPR each)
    const int o00 = c0.x << 4, o01 = c0.y << 4, o02 = c0.z << 4, o03 = c0.w << 4;
    const int o10 = c1.x << 4, o11 = c1.y << 4, o12 = c1.z << 4, o13 = c1.w << 4;

    vfloat4 r0[4], r1[4];
    // Pairwise issue order: (px0:c0,c1),(px1:...),... so px_i's pair is the
    // 2i-th/2i+1-th oldest load. "=&v" early-clobber: outputs must not alias
    // later loads' offset regs (R5 fault lesson). First wait: px0 pair ready.
    asm volatile(
        "global_load_dwordx4 %0, %8, %16 sc0\n\t"
        "global_load_dwordx4 %1, %9, %16 sc0\n\t"
        "global_load_dwordx4 %2, %10, %16 sc0\n\t"
        "global_load_dwordx4 %3, %11, %16 sc0\n\t"
        "global_load_dwordx4 %4, %12, %16 sc0\n\t"
        "global_load_dwordx4 %5, %13, %16 sc0\n\t"
        "global_load_dwordx4 %6, %14, %16 sc0\n\t"
        "global_load_dwordx4 %7, %15, %16 sc0\n\t"
        "s_waitcnt vmcnt(6)"
        : "=&v"(r0[0]), "=&v"(r1[0]), "=&v"(r0[1]), "=&v"(r1[1]),
          "=&v"(r0[2]), "=&v"(r1[2]), "=&v"(r0[3]), "=&v"(r1[3])
        : "v"(o00), "v"(o10), "v"(o01), "v"(o11),
          "v"(o02), "v"(o12), "v"(o03), "v"(o13),
          "s"(packed)
        : "memory");

    // all 4 pixels share a row (W divisible by 4)
    const float py = (float)(pix >> 11) + 0.5f;
    const float px_base = (float)(pix & (IMG_W - 1)) + 0.5f;

    float res[12];
    shade1(r0[0], r1[0], px_base, py, res);

    asm volatile("s_waitcnt vmcnt(4)" : "+v"(r0[1]), "+v"(r1[1]));
    shade1(r0[1], r1[1], px_base + 1.0f, py, res + 3);

    asm volatile("s_waitcnt vmcnt(2)" : "+v"(r0[2]), "+v"(r1[2]));
    shade1(r0[2], r1[2], px_base + 2.0f, py, res + 6);

    asm volatile("s_waitcnt vmcnt(0)" : "+v"(r0[3]), "+v"(r1[3]));
    shade1(r0[3], r1[3], px_base + 3.0f, py, res + 9);

    // normal cached stores: L2 write-back merges the partial-line pattern
    vfloat4* o = reinterpret_cast<vfloat4*>(out + (size_t)pix * 3);
    vfloat4 o0 = {res[0], res[1], res[2], res[3]};
    vfloat4 o1 = {res[4], res[5], res[6], res[7]};
    vfloat4 o2 = {res[8], res[9], res[10], res[11]};
    o[0] = o0;
    o[1] = o1;
    o[2] = o2;
}

// ---- fallback (ws too small): round-1 style direct gather, known-correct ----
__global__ __launch_bounds__(256) void voronoi_soft_fallback(
    const float* __restrict__ sites,
    const int*   __restrict__ cand0,
    const int*   __restrict__ cand1,
    float*       __restrict__ out)
{
    const int tid = blockIdx.x * blockDim.x + threadIdx.x;
    const int pix = tid * 4;
    const int4 c0 = *reinterpret_cast<const int4*>(cand0 + pix);
    const int4 c1 = *reinterpret_cast<const int4*>(cand1 + pix);
    const int idx0[4] = {c0.x, c0.y, c0.z, c0.w};
    const int idx1[4] = {c1.x, c1.y, c1.z, c1.w};
    const float py = (float)(pix >> 11) + 0.5f;
    const float px_base = (float)(pix & (IMG_W - 1)) + 0.5f;
    float res[12];
#pragma unroll
    for (int i = 0; i < 4; ++i) {
        const float px = px_base + (float)i;
        const float* s0 = sites + (size_t)idx0[i] * 5;
        const float* s1 = sites + (size_t)idx1[i] * 5;
        const float dx0 = px - s0[0], dy0 = py - s0[1];
        const float dx1 = px - s1[0], dy1 = py - s1[1];
        const float d0 = dx0 * dx0 + dy0 * dy0;
        const float d1 = dx1 * dx1 + dy1 * dy1;
        const float w = 1.0f / (1.0f + __expf(-(d1 - d0) * INV_SCALE_SQ));
        const float wc = 1.0f - w;
        res[i * 3 + 0] = w * s0[2] + wc * s1[2];
        res[i * 3 + 1] = w * s0[3] + wc * s1[3];
        res[i * 3 + 2] = w * s0[4] + wc * s1[4];
    }
    float4* o = reinterpret_cast<float4*>(out + (size_t)pix * 3);
    o[0] = make_float4(res[0], res[1], res[2], res[3]);
    o[1] = make_float4(res[4], res[5], res[6], res[7]);
    o[2] = make_float4(res[8], res[9], res[10], res[11]);
}

extern "C" void kernel_launch(void* const* d_in, const int* in_sizes, int n_in,
                              void* d_out, int out_size, void* d_ws, size_t ws_size,
                              hipStream_t stream) {
    const float* sites = (const float*)d_in[0];   // [65536, 5]
    const int*   cand0 = (const int*)d_in[1];     // [2048, 2048]
    const int*   cand1 = (const int*)d_in[2];     // [2048, 2048]
    float* out = (float*)d_out;                   // [2048, 2048, 3]

    const size_t packed_bytes = (size_t)N_SITES * sizeof(vfloat4);  // 1 MB
    if (ws_size >= packed_bytes) {
        vfloat4* packed = (vfloat4*)d_ws;
        repack_sites<<<N_SITES / 256, 256, 0, stream>>>(sites, packed);
        voronoi_soft_kernel<<<N_PIX / (4 * 256), 256, 0, stream>>>(packed, cand0, cand1, out);
    } else {
        voronoi_soft_fallback<<<N_PIX / (4 * 256), 256, 0, stream>>>(sites, cand0, cand1, out);
    }
}

// Round 9
// 130.339 us; speedup vs baseline: 1.0511x; 1.0230x over previous
//
#include <hip/hip_runtime.h>
#include <hip/hip_fp16.h>

// Soft Voronoi rasterizer: out[y][x][c] = w*s0.rgb + (1-w)*s1.rgb,
// w = sigmoid((d1-d0)*0.25), d_i = |pixel_center - site_i.xy|^2.
// Constants fixed by setup_inputs(): H=W=2048, N_SITES=65536.
//
// Ladder: R1 86us -> R3 packed 16B records (1 dwordx4/gather) 56us -> R4
// cached stores (not write-bound) -> R6 sc0 L1-bypass 49.5us -> R7 8px/thread
// REGRESSED (55.7) -> R8 staged vmcnt waits NEUTRAL (49.6). Model: device
// sustains ~170G scattered lane-req/s independent of per-wave scheduling.
// R9: untested axis = wave turnover UP: 1 px/thread, 2 gathers/thread, 4x
// wave count, minimal VGPR -> max occupancy. If flat, scattered-request
// throughput is the structural ceiling.

#define IMG_W 2048
#define IMG_H 2048
#define N_PIX (IMG_W * IMG_H)
#define N_SITES 65536
#define INV_SCALE_SQ 0.25f

typedef float vfloat4 __attribute__((ext_vector_type(4)));

// ---- pre-pass: [N,5] f32 -> [N] {x f32, y f32, (r,g) half2, (b,0) half2} ----
__global__ __launch_bounds__(256) void repack_sites(
    const float* __restrict__ sites, vfloat4* __restrict__ packed)
{
    const int i = blockIdx.x * blockDim.x + threadIdx.x;  // < N_SITES
    const float* s = sites + (size_t)i * 5;
    const __half2 rg = __floats2half2_rn(s[2], s[3]);
    const __half2 b0 = __floats2half2_rn(s[4], 0.0f);
    vfloat4 v;
    v.x = s[0];
    v.y = s[1];
    v.z = __uint_as_float(*reinterpret_cast<const unsigned int*>(&rg));
    v.w = __uint_as_float(*reinterpret_cast<const unsigned int*>(&b0));
    packed[i] = v;
}

__device__ __forceinline__ float3 unpack_rgb(const vfloat4& rec) {
    const unsigned int zu = __float_as_uint(rec.z);
    const unsigned int wu = __float_as_uint(rec.w);
    const __half2 rg = *reinterpret_cast<const __half2*>(&zu);
    const __half2 b0 = *reinterpret_cast<const __half2*>(&wu);
    const float2 rgf = __half22float2(rg);
    return make_float3(rgf.x, rgf.y, __half2float(b0.x));
}

// ---- main: 1 pixel/thread; 2 sc0 gathers, one drain; 3 dword stores ----
__global__ __launch_bounds__(256) void voronoi_soft_kernel(
    const vfloat4* __restrict__ packed, // [N_SITES] repacked records
    const int*     __restrict__ cand0,  // [H, W]
    const int*     __restrict__ cand1,  // [H, W]
    float*         __restrict__ out)    // [H, W, 3]
{
    const int pix = blockIdx.x * blockDim.x + threadIdx.x;  // grid == N_PIX

    // streamed once: nontemporal so they don't evict the site table from L2
    const int i0 = __builtin_nontemporal_load(cand0 + pix);
    const int i1 = __builtin_nontemporal_load(cand1 + pix);

    // byte offsets into the 16B-record table; saddr-form loads (1 VGPR each)
    const int o0 = i0 << 4;
    const int o1 = i1 << 4;

    // 2 L1-bypassing gathers, one drain. "=&v" early-clobber: outputs must
    // not alias the other load's offset reg (R5 fault lesson).
    vfloat4 r0, r1;
    asm volatile(
        "global_load_dwordx4 %0, %2, %4 sc0\n\t"
        "global_load_dwordx4 %1, %3, %4 sc0\n\t"
        "s_waitcnt vmcnt(0)"
        : "=&v"(r0), "=&v"(r1)
        : "v"(o0), "v"(o1), "s"(packed)
        : "memory");

    const float py = (float)(pix >> 11) + 0.5f;
    const float px = (float)(pix & (IMG_W - 1)) + 0.5f;

    const float dx0 = px - r0.x, dy0 = py - r0.y;
    const float dx1 = px - r1.x, dy1 = py - r1.y;
    const float d0 = dx0 * dx0 + dy0 * dy0;
    const float d1 = dx1 * dx1 + dy1 * dy1;
    const float t = (d1 - d0) * INV_SCALE_SQ;
    // stable at both tails: expf(+huge)=inf -> w=0; expf(-huge)=0 -> w=1
    const float w = 1.0f / (1.0f + __expf(-t));
    const float wc = 1.0f - w;

    const float3 cA = unpack_rgb(r0);
    const float3 cB = unpack_rgb(r1);

    // 12B/thread, wave-contiguous (768B span): L2 write-back merges lines
    float* o = out + (size_t)pix * 3;
    o[0] = w * cA.x + wc * cB.x;
    o[1] = w * cA.y + wc * cB.y;
    o[2] = w * cA.z + wc * cB.z;
}

// ---- fallback (ws too small): round-1 style direct gather, known-correct ----
__global__ __launch_bounds__(256) void voronoi_soft_fallback(
    const float* __restrict__ sites,
    const int*   __restrict__ cand0,
    const int*   __restrict__ cand1,
    float*       __restrict__ out)
{
    const int tid = blockIdx.x * blockDim.x + threadIdx.x;
    const int pix = tid * 4;
    const int4 c0 = *reinterpret_cast<const int4*>(cand0 + pix);
    const int4 c1 = *reinterpret_cast<const int4*>(cand1 + pix);
    const int idx0[4] = {c0.x, c0.y, c0.z, c0.w};
    const int idx1[4] = {c1.x, c1.y, c1.z, c1.w};
    const float py = (float)(pix >> 11) + 0.5f;
    const float px_base = (float)(pix & (IMG_W - 1)) + 0.5f;
    float res[12];
#pragma unroll
    for (int i = 0; i < 4; ++i) {
        const float px = px_base + (float)i;
        const float* s0 = sites + (size_t)idx0[i] * 5;
        const float* s1 = sites + (size_t)idx1[i] * 5;
        const float dx0 = px - s0[0], dy0 = py - s0[1];
        const float dx1 = px - s1[0], dy1 = py - s1[1];
        const float d0 = dx0 * dx0 + dy0 * dy0;
        const float d1 = dx1 * dx1 + dy1 * dy1;
        const float w = 1.0f / (1.0f + __expf(-(d1 - d0) * INV_SCALE_SQ));
        const float wc = 1.0f - w;
        res[i * 3 + 0] = w * s0[2] + wc * s1[2];
        res[i * 3 + 1] = w * s0[3] + wc * s1[3];
        res[i * 3 + 2] = w * s0[4] + wc * s1[4];
    }
    float4* o = reinterpret_cast<float4*>(out + (size_t)pix * 3);
    o[0] = make_float4(res[0], res[1], res[2], res[3]);
    o[1] = make_float4(res[4], res[5], res[6], res[7]);
    o[2] = make_float4(res[8], res[9], res[10], res[11]);
}

extern "C" void kernel_launch(void* const* d_in, const int* in_sizes, int n_in,
                              void* d_out, int out_size, void* d_ws, size_t ws_size,
                              hipStream_t stream) {
    const float* sites = (const float*)d_in[0];   // [65536, 5]
    const int*   cand0 = (const int*)d_in[1];     // [2048, 2048]
    const int*   cand1 = (const int*)d_in[2];     // [2048, 2048]
    float* out = (float*)d_out;                   // [2048, 2048, 3]

    const size_t packed_bytes = (size_t)N_SITES * sizeof(vfloat4);  // 1 MB
    if (ws_size >= packed_bytes) {
        vfloat4* packed = (vfloat4*)d_ws;
        repack_sites<<<N_SITES / 256, 256, 0, stream>>>(sites, packed);
        voronoi_soft_kernel<<<N_PIX / 256, 256, 0, stream>>>(packed, cand0, cand1, out);
    } else {
        voronoi_soft_fallback<<<N_PIX / (4 * 256), 256, 0, stream>>>(sites, cand0, cand1, out);
    }
}